// Round 1
// baseline (72.905 us; speedup 1.0000x reference)
//
#include <hip/hip_runtime.h>

// CenterLoss: x [B=4096, D=512] f32, centers [C=10000, D=512] f32, labels [B] i32.
// Masked distmat keeps only dist[i, labels[i]]; zeros clamp to 1e-12.
// loss = (sum_i clamp(||x_i - c_{l_i}||^2, 1e-12, 1e12) + B*(C-1)*1e-12) / (B*C) / B

constexpr int B = 4096;
constexpr int C = 10000;
constexpr int D = 512;

// One wave (64 lanes) per row; 4 waves per 256-thread block.
// Each lane loads 2 float4 of x and of the gathered center row (contiguous 2KB
// per wave -> fully coalesced), accumulates (x-c)^2, wave shuffle-reduce.
__global__ void __launch_bounds__(256) row_dist_kernel(
    const float* __restrict__ x, const float* __restrict__ centers,
    const int* __restrict__ labels, float* __restrict__ row_out) {
  const int row  = (blockIdx.x << 2) + (threadIdx.x >> 6);
  const int lane = threadIdx.x & 63;
  if (row >= B) return;

  const int lbl = labels[row];
  const float4* xr = reinterpret_cast<const float4*>(x)       + (size_t)row * (D / 4);
  const float4* cr = reinterpret_cast<const float4*>(centers) + (size_t)lbl * (D / 4);

  float acc = 0.f;
#pragma unroll
  for (int j = 0; j < (D / 4) / 64; ++j) {   // 2 iterations
    const float4 a = xr[lane + j * 64];
    const float4 b = cr[lane + j * 64];
    const float d0 = a.x - b.x, d1 = a.y - b.y, d2 = a.z - b.z, d3 = a.w - b.w;
    acc = fmaf(d0, d0, fmaf(d1, d1, fmaf(d2, d2, fmaf(d3, d3, acc))));
  }

#pragma unroll
  for (int off = 32; off; off >>= 1) acc += __shfl_down(acc, off, 64);

  if (lane == 0) {
    // faithful clamp on the kept entry
    row_out[row] = fminf(fmaxf(acc, 1e-12f), 1e12f);
  }
}

// Single-block deterministic reduction of the 4096 row distances (f64 accum),
// plus the clamp correction for the B*(C-1) masked zeros, then the two divides.
__global__ void __launch_bounds__(1024) reduce_kernel(
    const float* __restrict__ row_dist, float* __restrict__ out) {
  __shared__ double lds[16];
  const int t = threadIdx.x;

  double s = 0.0;
#pragma unroll
  for (int j = 0; j < B / 1024; ++j)         // 4 values per thread
    s += (double)row_dist[t + j * 1024];

#pragma unroll
  for (int off = 32; off; off >>= 1) s += __shfl_down(s, off, 64);

  const int wave = t >> 6, lane = t & 63;
  if (lane == 0) lds[wave] = s;
  __syncthreads();

  if (t == 0) {
    double tot = 0.0;
#pragma unroll
    for (int w = 0; w < 16; ++w) tot += lds[w];
    tot += (double)B * (double)(C - 1) * 1e-12;          // clamped masked zeros
    const double denom = (double)B * (double)C * (double)B;
    out[0] = (float)(tot / denom);
  }
}

extern "C" void kernel_launch(void* const* d_in, const int* in_sizes, int n_in,
                              void* d_out, int out_size, void* d_ws, size_t ws_size,
                              hipStream_t stream) {
  const float* x       = (const float*)d_in[0];
  const float* centers = (const float*)d_in[1];
  const int*   labels  = (const int*)d_in[2];
  float* out = (float*)d_out;
  float* ws  = (float*)d_ws;   // 4096 floats of per-row distances

  row_dist_kernel<<<B / 4, 256, 0, stream>>>(x, centers, labels, ws);
  reduce_kernel<<<1, 1024, 0, stream>>>(ws, out);
}